// Round 11
// baseline (488.769 us; speedup 1.0000x reference)
//
#include <hip/hip_runtime.h>
#include <math.h>

#define QD 256
#define QN 1024
#define NTOK 65536
#define TT 8192

typedef __bf16 bf16x8 __attribute__((ext_vector_type(8)));
typedef float  f32x16 __attribute__((ext_vector_type(16)));
typedef unsigned short ushort_t;
typedef unsigned short us8 __attribute__((ext_vector_type(8)));

// LDS map (bytes), total 76288 -> 2 blocks/CU (152.6 KB of 160 KB)
#define XB  0        // X[64][260] f32 = 66560 (patches, then t)
#define XSTR 260
#define WS  66560    // wsS[256]
#define P1O 67584    // p1S[256]
#define MP  68608    // muP[64][8]
#define SP  70656    // sqP[64][4]
#define LM  71680    // lnMu[64]
#define LR  71936    // lnRs[64]
#define RV  72192    // redV[64][8]
#define RI  74240    // redI[64][8]
#define SMEM_TOTAL 76288

// exact 3-way bf16 split (truncation; x = h+m+l to ~2^-25|x|)
__device__ __forceinline__ void split3(float x, ushort_t& h, ushort_t& m, ushort_t& l) {
    unsigned int xu = __float_as_uint(x);
    h = (ushort_t)(xu >> 16);
    float hf = __uint_as_float(xu & 0xFFFF0000u);
    float r1 = x - hf;                       // exact
    unsigned int r1u = __float_as_uint(r1);
    m = (ushort_t)(r1u >> 16);
    float mf = __uint_as_float(r1u & 0xFFFF0000u);
    float r2 = r1 - mf;                      // exact
    l = (ushort_t)(__float_as_uint(r2) >> 16);
}
__device__ __forceinline__ f32x16 MF(bf16x8 a, bf16x8 b, f32x16 c) {
    return __builtin_amdgcn_mfma_f32_32x32x16_bf16(a, b, c, 0, 0, 0);
}
union U8B { us8 u; bf16x8 b; };

// ---------- k_cbnorm: l2-normalize codebook -> 3 bf16 planes in frag layout ----------
// cbp[p][kc 16][nt 32][lane 64][8]: element (code c, k): nt=c>>5, lane=((k>>3)&1)*32+(c&31), j=k&7
__global__ __launch_bounds__(64) void k_cbnorm(const float* __restrict__ cb,
                                               ushort_t* __restrict__ cbp) {
    int c = blockIdx.x, lane = threadIdx.x;
    float4 v = ((const float4*)(cb + (size_t)c * QD))[lane];
    float ss = v.x*v.x + v.y*v.y + v.z*v.z + v.w*v.w;
    #pragma unroll
    for (int off = 32; off > 0; off >>= 1) ss += __shfl_down(ss, off);
    ss = __shfl(ss, 0);
    float inv = 1.0f / fmaxf(sqrtf(ss), 1e-12f);
    float vals[4] = {v.x*inv, v.y*inv, v.z*inv, v.w*inv};
    #pragma unroll
    for (int i = 0; i < 4; ++i) {
        int k = 4*lane + i;
        ushort_t hb, mb, lb; split3(vals[i], hb, mb, lb);
        size_t base = ((size_t)(k>>4)*32 + (c>>5))*512 + (((k>>3)&1)*32 + (c&31))*8 + (k&7);
        cbp[base] = hb;
        cbp[base + (size_t)16*32*512] = mb;
        cbp[base + (size_t)2*16*32*512] = lb;
    }
}

// ---------- k_prep: [M|G] = convw^T @ [proj | convw] -> 3 bf16 planes; wsum; p1 ----------
// w2p[p][kc 16][nt 16][lane 64][8]
__global__ __launch_bounds__(256) void k_prep(const float* __restrict__ convw,
                                              const float* __restrict__ proj,
                                              ushort_t* __restrict__ w2p,
                                              float* __restrict__ wsum,
                                              float* __restrict__ p1) {
    int col = blockIdx.x, t = threadIdx.x;
    if (col < 512) {
        __shared__ float colv[512];
        const float* src = (col < 256) ? (proj + col) : (convw + (col - 256));
        colv[t]       = src[(size_t)t * 256];
        colv[t + 256] = src[(size_t)(t + 256) * 256];
        __syncthreads();
        float acc = 0.f;
        for (int d = 0; d < 512; ++d) acc += convw[d * 256 + t] * colv[d];
        int k = t;
        ushort_t hb, mb, lb; split3(acc, hb, mb, lb);
        size_t base = ((size_t)(k>>4)*16 + (col>>5))*512 + (((k>>3)&1)*32 + (col&31))*8 + (k&7);
        w2p[base] = hb;
        w2p[base + (size_t)16*16*512] = mb;
        w2p[base + (size_t)2*16*16*512] = lb;
    } else if (col == 512) {
        float s = 0.f;
        for (int d = 0; d < 512; ++d) s += convw[d*256 + t];
        wsum[t] = s;
    } else {
        float s = 0.f;
        for (int d = 0; d < 512; ++d) s += proj[d*256 + t];
        p1[t] = s;
    }
}

// ---------- k_mega: x fp32 in LDS, split-on-the-fly A, global->reg B, 2 blocks/CU ----------
__global__ __launch_bounds__(512, 4) void k_mega(const float* __restrict__ fbank,
                                                 const ushort_t* __restrict__ w2p,
                                                 const ushort_t* __restrict__ cbp,
                                                 const float* __restrict__ wsum,
                                                 const float* __restrict__ p1,
                                                 int* __restrict__ out) {
    extern __shared__ char smem[];
    float* X   = (float*)(smem + XB);
    float* wsS = (float*)(smem + WS);
    float* p1S = (float*)(smem + P1O);
    float* muP = (float*)(smem + MP);
    float* sqP = (float*)(smem + SP);
    float* lnMu= (float*)(smem + LM);
    float* lnRs= (float*)(smem + LR);
    float* redV= (float*)(smem + RV);
    int*   redI= (int*)(smem + RI);

    int tid = threadIdx.x;
    int n0 = blockIdx.x * 64;
    int w = tid >> 6, lane = tid & 63, n31 = lane & 31, h = lane >> 5;
    const char* w2pc = (const char*)w2p;
    const char* cbpc = (const char*)cbp;
    size_t loff = (size_t)lane * 16;

    if (tid < 256) wsS[tid] = wsum[tid];
    else           p1S[tid - 256] = p1[tid - 256];

    // ---- stage fbank -> X fp32; token-major in lane: coalesced reads, conflict-free writes
    #pragma unroll
    for (int i = 0; i < 2; ++i) {
        int s = tid + 512*i;
        int j = s & 63, ph = s >> 6;
        int n = n0 + j;
        int b = n >> 12, r = n & 4095, th = r >> 3, wm = r & 7;
        const float4* src = (const float4*)(fbank + ((size_t)(b*TT + th*16 + ph))*128 + wm*16);
        float4* dst = (float4*)(X + j*XSTR + ph*16);
        #pragma unroll
        for (int c = 0; c < 4; ++c) dst[c] = src[c];
    }
    __syncthreads();

    f32x16 acc[2][2];
    #pragma unroll
    for (int a = 0; a < 2; ++a)
        #pragma unroll
        for (int b2 = 0; b2 < 2; ++b2)
            #pragma unroll
            for (int r2 = 0; r2 < 16; ++r2) acc[a][b2][r2] = 0.f;

    // read x fragment for (mt,kc) and split into 3 bf16 planes in registers
    auto loadSplitA = [&](int kc, bf16x8 (&a)[3][2]) {
        #pragma unroll
        for (int mt = 0; mt < 2; ++mt) {
            const float* xs = X + (mt*32 + n31)*XSTR + kc*16 + h*8;
            float4 x0 = *(const float4*)xs;
            float4 x1 = *(const float4*)(xs + 4);
            float v[8] = {x0.x, x0.y, x0.z, x0.w, x1.x, x1.y, x1.z, x1.w};
            U8B hv, mv, lv;
            #pragma unroll
            for (int j = 0; j < 8; ++j) {
                ushort_t a_, b_, c_; split3(v[j], a_, b_, c_);
                hv.u[j] = a_; mv.u[j] = b_; lv.u[j] = c_;
            }
            a[0][mt] = hv.b; a[1][mt] = mv.b; a[2][mt] = lv.b;
        }
    };
    auto mfma6 = [&](bf16x8 (&a)[3][2], bf16x8 (&b)[3][2]) {
        #pragma unroll
        for (int q = 0; q < 3; ++q)
            #pragma unroll
            for (int p = 0; p < 3; ++p)
                if (p + q <= 2) {
                    acc[0][0] = MF(a[p][0], b[q][0], acc[0][0]);
                    acc[0][1] = MF(a[p][0], b[q][1], acc[0][1]);
                    acc[1][0] = MF(a[p][1], b[q][0], acc[1][0]);
                    acc[1][1] = MF(a[p][1], b[q][1], acc[1][1]);
                }
    };

    // ================= GEMM1: V[64][512] = patch @ [M|G] =================
    for (int kc = 0; kc < 16; ++kc) {
        bf16x8 b[3][2];
        #pragma unroll
        for (int q = 0; q < 3; ++q) {     // issue B loads first (L2 latency under split)
            const char* gp = w2pc + (size_t)((q*16 + kc)*16 + 2*w)*1024;
            b[q][0] = *(const bf16x8*)(gp + loff);
            b[q][1] = *(const bf16x8*)(gp + 1024 + loff);
        }
        bf16x8 a[3][2];
        loadSplitA(kc, a);
        mfma6(a, b);
    }

    // ================= LN epilogue (x fp32 already in LDS) =================
    {   // mu partials: 8 threads per token, interleaved k for bank spread
        int tok = tid >> 3, part = tid & 7;
        const float* pr = X + tok*XSTR;
        float s = 0.f;
        #pragma unroll
        for (int i2 = 0; i2 < 32; ++i2) { int k = part + 8*i2; s += pr[k]*wsS[k]; }
        muP[tok*8 + part] = s;
    }
    if (w >= 4) {      // sumsq = V_G . patch (waves 4..7 hold G cols)
        int wv = w - 4;
        #pragma unroll
        for (int mh = 0; mh < 2; ++mh)
            #pragma unroll
            for (int reg = 0; reg < 16; ++reg) {
                int row = (reg&3) + 8*(reg>>2) + 4*h;
                const float* xr = X + (mh*32 + row)*XSTR + 64*wv;
                float sv = acc[mh][0][reg]*xr[n31] + acc[mh][1][reg]*xr[32 + n31];
                #pragma unroll
                for (int msk = 1; msk < 32; msk <<= 1) sv += __shfl_xor(sv, msk);
                if (n31 == 0) sqP[(mh*32 + row)*4 + wv] = sv;
            }
    }
    __syncthreads();
    if (tid < 64) {
        float pm = 0.f, sq = 0.f;
        #pragma unroll
        for (int p = 0; p < 8; ++p) pm += muP[tid*8 + p];
        #pragma unroll
        for (int v2 = 0; v2 < 4; ++v2) sq += sqP[tid*4 + v2];
        float m_ = pm * (1.f/512.f);
        float var = sq * (1.f/512.f) - m_*m_;
        lnMu[tid] = m_;
        lnRs[tid] = rsqrtf(var + 1e-5f);     // positive scale: argmax-neutral
    }
    __syncthreads();
    if (w < 4) {       // t = rs*(V - mu*p1) written fp32 into X (waves 0..3 hold M cols)
        #pragma unroll
        for (int ntl = 0; ntl < 2; ++ntl) {
            int q = 64*w + 32*ntl + n31;
            float p1v = p1S[q];
            #pragma unroll
            for (int mt = 0; mt < 2; ++mt)
                #pragma unroll
                for (int reg = 0; reg < 16; ++reg) {
                    int row = (reg&3) + 8*(reg>>2) + 4*h;
                    int tk = 32*mt + row;
                    X[(mt*32 + row)*XSTR + q] = lnRs[tk]*(acc[mt][ntl][reg] - lnMu[tk]*p1v);
                }
        }
    }
    __syncthreads();

    // ================= GEMM2 + argmax: sim = t @ cbn^T =================
    for (int sweep = 0; sweep < 2; ++sweep) {
        #pragma unroll
        for (int a = 0; a < 2; ++a)
            #pragma unroll
            for (int b2 = 0; b2 < 2; ++b2)
                #pragma unroll
                for (int r2 = 0; r2 < 16; ++r2) acc[a][b2][r2] = 0.f;

        for (int kc = 0; kc < 16; ++kc) {
            bf16x8 b[3][2];
            #pragma unroll
            for (int q = 0; q < 3; ++q) {
                const char* gp = cbpc + (size_t)((q*16 + kc)*32 + 16*sweep + 2*w)*1024;
                b[q][0] = *(const bf16x8*)(gp + loff);
                b[q][1] = *(const bf16x8*)(gp + 1024 + loff);
            }
            bf16x8 a[3][2];
            loadSplitA(kc, a);
            mfma6(a, b);
        }
        // per-sweep fold -> lane reduce -> merge into redV (no persistent best regs)
        #pragma unroll
        for (int mt = 0; mt < 2; ++mt)
            #pragma unroll
            for (int reg = 0; reg < 16; ++reg) {
                int c0 = 512*sweep + 64*w + n31;     // ntl=0 ; c1 = c0+32
                float v0 = acc[mt][0][reg], v1 = acc[mt][1][reg];
                float bv = (v1 > v0) ? v1 : v0;      // tie keeps lower code c0
                int   bi = (v1 > v0) ? (c0 + 32) : c0;
                #pragma unroll
                for (int msk = 1; msk < 32; msk <<= 1) {
                    float ov = __shfl_xor(bv, msk);
                    int   oi = __shfl_xor(bi, msk);
                    if (ov > bv || (ov == bv && oi < bi)) { bv = ov; bi = oi; }
                }
                if (n31 == 0) {
                    int row = (reg&3) + 8*(reg>>2) + 4*h;
                    int slot = (32*mt + row)*8 + w;
                    if (sweep == 0) { redV[slot] = bv; redI[slot] = bi; }
                    else if (bv > redV[slot]) { redV[slot] = bv; redI[slot] = bi; }
                }
            }
    }
    __syncthreads();
    if (tid < 64) {
        float bv = redV[tid*8]; int bi = redI[tid*8];
        #pragma unroll
        for (int p = 1; p < 8; ++p) {
            float ov = redV[tid*8 + p]; int oi = redI[tid*8 + p];
            if (ov > bv || (ov == bv && oi < bi)) { bv = ov; bi = oi; }
        }
        out[n0 + tid] = bi;
    }
}

extern "C" void kernel_launch(void* const* d_in, const int* in_sizes, int n_in,
                              void* d_out, int out_size, void* d_ws, size_t ws_size,
                              hipStream_t stream) {
    const float* fbank = (const float*)d_in[0];   // 16 x 8192 x 128
    const float* convw = (const float*)d_in[1];   // [512][256]
    const float* proj  = (const float*)d_in[2];   // [512][256]
    const float* cbook = (const float*)d_in[3];   // [1024][256]
    int* out = (int*)d_out;                       // 65536 int32

    char* ws = (char*)d_ws;
    ushort_t* cbp = (ushort_t*)ws;                   // 1.5 MB code planes
    ushort_t* w2p = (ushort_t*)(ws + 0x180000);      // 768 KB weight planes
    float* wsum   = (float*)(ws + 0x240000);         // 1 KB
    float* p1     = (float*)(ws + 0x241000);         // 1 KB

    (void)hipFuncSetAttribute((const void*)k_mega,
                              hipFuncAttributeMaxDynamicSharedMemorySize, SMEM_TOTAL);

    hipLaunchKernelGGL(k_cbnorm, dim3(QN),  dim3(64),  0, stream, cbook, cbp);
    hipLaunchKernelGGL(k_prep,   dim3(514), dim3(256), 0, stream, convw, proj, w2p, wsum, p1);
    hipLaunchKernelGGL(k_mega,   dim3(NTOK/64), dim3(512), SMEM_TOTAL, stream,
                       fbank, w2p, cbp, wsum, p1, out);
}